// Round 6
// baseline (413.325 us; speedup 1.0000x reference)
//
#include <hip/hip_runtime.h>
#include <stdint.h>

// TBNN fused, split-bf16 (hi+lo) 3-pass MFMA for fp32-grade accuracy.
// Round-6: TPB=512, 1 block/CU (LDS 144KB), 2 waves/SIMD. Merged layer phase
// (one AvH+AvL read pair -> P3+P1+P2 = 3 MFMAs), 4 barriers/tile, PTILE=256
// (staging 1KB/pt). Conflict-free (col&15)<<4 XOR swizzle on prep + read.

#define NPTS   1000000
#define TPB    512
#define NBLKS  256
#define PTILE  256
#define NT     ((NPTS + PTILE - 1) / PTILE)

typedef uint32_t u32;
typedef __attribute__((ext_vector_type(4)))  u32   u32x4;
typedef __attribute__((ext_vector_type(8)))  short s16x8;
typedef __attribute__((ext_vector_type(16))) float f32x16;
typedef __attribute__((ext_vector_type(4), aligned(4))) float f32x4u;

// ---- workspace layout (prep output, exact LDS images) ----
#define WS_L(l)   ((l)*65536)              // layers 2..5: 128 rows x 512B [hi256|lo256], swz (of&15)<<4
#define WS_TAIL   262144                   // heads 16x512B + W1 + bias (one 16KB block)
#define WS_W1     (262144 + 8192)
#define WS_BIAS   (262144 + 12288)

// ---- LDS layout (144KB) ----
#define LDS_BUF0   0
#define LDS_BUF1   65536
#define LDS_HEADS  131072
#define LDS_W1     (131072 + 8192)
#define LDS_BIAS   (131072 + 12288)
#define LDS_TOTAL  147456

#define MFMA(a,b,c) __builtin_amdgcn_mfma_f32_32x32x16_bf16((a),(b),(c),0,0,0)
#define BC16(v)     __builtin_bit_cast(s16x8, (v))

__device__ __forceinline__ u32 cvtpk(float lo, float hi) {
    u32 r;
    asm("v_cvt_pk_bf16_f32 %0, %1, %2" : "=v"(r) : "v"(lo), "v"(hi));
    return r;
}
__device__ __forceinline__ float lo2f(u32 p){ return __builtin_bit_cast(float, p << 16); }
__device__ __forceinline__ float hi2f(u32 p){ return __builtin_bit_cast(float, p & 0xffff0000u); }
__device__ __forceinline__ uint16_t f2bf(float f) {   // RNE fp32->bf16
    u32 u = __builtin_bit_cast(u32, f);
    return (uint16_t)((u + 0x7fffu + ((u >> 16) & 1u)) >> 16);
}
__device__ __forceinline__ float b2f(uint16_t h){ return __builtin_bit_cast(float, (u32)h << 16); }

// cooperative global->LDS DMA: 512 thr x 16B = 8KB/iter, linear image copy
__device__ __forceinline__ void stageN(const char* g, char* l, int tid, int nbytes) {
    const int w = tid >> 6, ln = tid & 63;
    const char* gp = g + w*1024 + ln*16;
    char* lp = l + w*1024;                 // wave-uniform LDS base (lane offset HW-implicit)
    #pragma unroll
    for (int i = 0; i < 8; ++i) {
        if (i*8192 >= nbytes) break;
        __builtin_amdgcn_global_load_lds(
            (const __attribute__((address_space(1))) uint32_t*)(gp + i*8192),
            (__attribute__((address_space(3))) uint32_t*)(lp + i*8192), 16, 0, 0);
    }
}

// ---------------- prep: split + swizzle weights into ws ----------------
extern "C" __global__ void __launch_bounds__(256)
tbnn_prep(const float* __restrict__ W1, const float* __restrict__ b1,
          const float* __restrict__ W2, const float* __restrict__ b2,
          const float* __restrict__ W3, const float* __restrict__ b3,
          const float* __restrict__ W4, const float* __restrict__ b4,
          const float* __restrict__ W5, const float* __restrict__ b5,
          const float* __restrict__ Wc, const float* __restrict__ bc,
          const float* __restrict__ Wg1,const float* __restrict__ bg1,
          const float* __restrict__ Wg2,const float* __restrict__ bg2,
          const float* __restrict__ Wg3,const float* __restrict__ bg3,
          char* __restrict__ ws)
{
    int idx = blockIdx.x*256 + threadIdx.x;
    if (idx < 65536) {                         // hidden layers 2..5
        int l = idx >> 14, r = idx & 16383, ifc = r >> 7, of = r & 127;
        const float* Wt = (l==0)?W2:(l==1)?W3:(l==2)?W4:W5;
        float w = Wt[ifc*128 + of];
        uint16_t hb = f2bf(w);
        uint16_t lb = f2bf(w - b2f(hb));
        char* row = ws + WS_L(l) + of*512;
        int o = (2*ifc) ^ ((of&15)<<4);        // closed within [0,256)
        *(uint16_t*)(row + o)       = hb;
        *(uint16_t*)(row + 256 + o) = lb;
    } else if (idx < 65536 + 2048) {           // heads: rows 0..9 Wc, 10..12 Wg, 13..15 zero
        int j = idx - 65536, of = j >> 7, ifc = j & 127;
        float v = 0.f;
        if      (of < 10)  v = Wc[ifc*10 + of];
        else if (of == 10) v = Wg1[ifc];
        else if (of == 11) v = Wg2[ifc];
        else if (of == 12) v = Wg3[ifc];
        uint16_t hb = f2bf(v);
        uint16_t lb = f2bf(v - b2f(hb));
        char* row = ws + WS_TAIL + of*512;
        int o = (2*ifc) ^ ((of&15)<<4);
        *(uint16_t*)(row + o)       = hb;
        *(uint16_t*)(row + 256 + o) = lb;
    } else if (idx < 65536 + 2048 + 128) {     // W1 rows: [Wh(5),b,Wl(5),Wh(5)]
        int of = idx - (65536 + 2048);
        uint16_t* dst = (uint16_t*)(ws + WS_W1 + of*32);
        #pragma unroll
        for (int s = 0; s < 5; ++s) {
            float w = W1[s*128 + of];
            uint16_t hb = f2bf(w);
            dst[s]      = hb;
            dst[6 + s]  = f2bf(w - b2f(hb));
            dst[11 + s] = hb;
        }
        dst[5] = f2bf(b1[of]);
    } else if (idx < 65536 + 2048 + 128 + 544) { // bias arrays (bf16)
        int j = idx - (65536 + 2048 + 128);
        float v = 0.f;
        if (j < 512) {
            int l = j >> 7, of = j & 127;
            const float* bt = (l==0)?b2:(l==1)?b3:(l==2)?b4:b5;
            v = bt[of];
        } else {
            int of = j - 512;
            if      (of < 10)  v = bc[of];
            else if (of == 10) v = bg1[0];
            else if (of == 11) v = bg2[0];
            else if (of == 12) v = bg3[0];
        }
        *(uint16_t*)(ws + WS_BIAS + j*2) = f2bf(v);
    }
}

// merged layer phase: per k read 4 AvH + 4 AvL, 12 MFMAs (P3: H*Bl, P1: H*Bh, P2: L*Bh)
#define LAYER(lc, BUFOFF) do {                                                   \
    const char* wb = smem + (BUFOFF);                                            \
    __builtin_amdgcn_s_setprio(1);                                               \
    _Pragma("unroll")                                                            \
    for (int k = 0; k < 8; ++k) {                                                \
        int so = (k*32 + hib) ^ sm;                                              \
        const char* rp = wb + col*512 + so;                                      \
        u32x4 H0 = *(const u32x4*)(rp);                                          \
        u32x4 L0v = *(const u32x4*)(rp + 256);                                   \
        u32x4 H1 = *(const u32x4*)(rp + 32*512);                                 \
        u32x4 L1v = *(const u32x4*)(rp + 32*512 + 256);                          \
        u32x4 H2 = *(const u32x4*)(rp + 64*512);                                 \
        u32x4 L2v = *(const u32x4*)(rp + 64*512 + 256);                          \
        u32x4 H3 = *(const u32x4*)(rp + 96*512);                                 \
        u32x4 L3v = *(const u32x4*)(rp + 96*512 + 256);                          \
        s16x8 bl = BC16(Bl[k]), bh = BC16(Bh[k]);                                \
        acc[0] = MFMA(BC16(H0), bl, (k==0)?zf:acc[0]);                           \
        acc[1] = MFMA(BC16(H1), bl, (k==0)?zf:acc[1]);                           \
        acc[2] = MFMA(BC16(H2), bl, (k==0)?zf:acc[2]);                           \
        acc[3] = MFMA(BC16(H3), bl, (k==0)?zf:acc[3]);                           \
        acc[0] = MFMA(BC16(H0), bh, acc[0]);                                     \
        acc[1] = MFMA(BC16(H1), bh, acc[1]);                                     \
        acc[2] = MFMA(BC16(H2), bh, acc[2]);                                     \
        acc[3] = MFMA(BC16(H3), bh, acc[3]);                                     \
        acc[0] = MFMA(BC16(L0v), bh, acc[0]);                                    \
        acc[1] = MFMA(BC16(L1v), bh, acc[1]);                                    \
        acc[2] = MFMA(BC16(L2v), bh, acc[2]);                                    \
        acc[3] = MFMA(BC16(L3v), bh, acc[3]);                                    \
    }                                                                            \
    _Pragma("unroll")                                                            \
    for (int ot = 0; ot < 4; ++ot) {                                             \
        u32 bw = (u32)*(const uint16_t*)(smem + LDS_BIAS + ((lc)*128 + ot*32 + col)*2); \
        u32x4 Ab; Ab[0] = hi ? 0u : bw; Ab[1]=0u; Ab[2]=0u; Ab[3]=0u;            \
        acc[ot] = MFMA(BC16(Ab), BC16(Bc), acc[ot]);                             \
    }                                                                            \
    __builtin_amdgcn_s_setprio(0);                                               \
    convert();                                                                   \
} while (0)

// ---------------- main ----------------
extern "C" __global__ void __launch_bounds__(TPB)
tbnn_main(const float* __restrict__ x, const float* __restrict__ tb,
          const char* __restrict__ ws, float* __restrict__ out)
{
    extern __shared__ char smem[];
    const int tid  = threadIdx.x;
    const int wave = tid >> 6;
    const int lane = tid & 63;
    const int col  = lane & 31;
    const int hi   = lane >> 5;
    const int sm   = (col & 15) << 4;  // full-width swizzle: 16 distinct slots per quarter
    const int hib  = hi * 16;          // hi half reads k-slots 8..15

    // prologue: tail + L2 + L3 images
    stageN(ws + WS_TAIL, smem + LDS_HEADS, tid, 16384);
    stageN(ws + WS_L(0), smem + LDS_BUF0,  tid, 65536);
    stageN(ws + WS_L(1), smem + LDS_BUF1,  tid, 65536);
    __syncthreads();

    u32x4 Bc; Bc[0] = hi ? 0u : 0x00003F80u; Bc[1]=0u; Bc[2]=0u; Bc[3]=0u; // bias k-step (1.0 at k=0)
    f32x16 zf;
    #pragma unroll
    for (int i = 0; i < 16; ++i) zf[i] = 0.f;

    for (int t = blockIdx.x; t < NT; t += gridDim.x) {
        const int pb = t*PTILE + wave*32;
        const int p  = pb + col;

        f32x16 acc[4];
        u32x4  Bh[8], Bl[8];

        // MFMA C-layout -> next-layer B fragments (hi + lo), relu fused
        auto convert = [&]() {
            #pragma unroll
            for (int ot = 0; ot < 4; ++ot) {
                f32x16 a = acc[ot];
                #pragma unroll
                for (int h2 = 0; h2 < 2; ++h2) {
                    float e0 = fmaxf(a[8*h2+0], 0.f), e1 = fmaxf(a[8*h2+1], 0.f);
                    float e2 = fmaxf(a[8*h2+2], 0.f), e3 = fmaxf(a[8*h2+3], 0.f);
                    float e4 = fmaxf(a[8*h2+4], 0.f), e5 = fmaxf(a[8*h2+5], 0.f);
                    float e6 = fmaxf(a[8*h2+6], 0.f), e7 = fmaxf(a[8*h2+7], 0.f);
                    u32 h01 = cvtpk(e0,e1), h23 = cvtpk(e2,e3);
                    u32 h45 = cvtpk(e4,e5), h67 = cvtpk(e6,e7);
                    u32 l01 = cvtpk(e0 - lo2f(h01), e1 - hi2f(h01));
                    u32 l23 = cvtpk(e2 - lo2f(h23), e3 - hi2f(h23));
                    u32 l45 = cvtpk(e4 - lo2f(h45), e5 - hi2f(h45));
                    u32 l67 = cvtpk(e6 - lo2f(h67), e7 - hi2f(h67));
                    auto sh1 = __builtin_amdgcn_permlane32_swap(h01, h45, false, false);
                    auto sh2 = __builtin_amdgcn_permlane32_swap(h23, h67, false, false);
                    u32x4 fh; fh[0]=sh1[0]; fh[1]=sh2[0]; fh[2]=sh1[1]; fh[3]=sh2[1];
                    Bh[2*ot+h2] = fh;
                    auto sl1 = __builtin_amdgcn_permlane32_swap(l01, l45, false, false);
                    auto sl2 = __builtin_amdgcn_permlane32_swap(l23, l67, false, false);
                    u32x4 fl; fl[0]=sl1[0]; fl[1]=sl2[0]; fl[2]=sl1[1]; fl[3]=sl2[1];
                    Bl[2*ot+h2] = fl;
                }
            }
        };

        { // ---- L1: one K=16 step packs Wh*xh + b + Wl*xh + Wh*xl ----
            float x0=0.f,x1=0.f,x2=0.f,x3=0.f,x4=0.f;
            if (p < NPTS) {
                const float* xp = x + (size_t)p*5;
                f32x4u v = *(const f32x4u*)xp;
                x0=v.x; x1=v.y; x2=v.z; x3=v.w; x4=xp[4];
            }
            float h0 = lo2f(cvtpk(x0,x0)), l0 = x0 - h0;
            float h1 = lo2f(cvtpk(x1,x1)), l1 = x1 - h1;
            float h2 = lo2f(cvtpk(x2,x2)), l2 = x2 - h2;
            float h3 = lo2f(cvtpk(x3,x3)), l3 = x3 - h3;
            float h4 = lo2f(cvtpk(x4,x4)), l4 = x4 - h4;
            u32x4 Bx;
            if (hi == 0) {   // k0..7 : [xh0..4, 1, xh0, xh1]
                Bx[0] = cvtpk(h0,h1); Bx[1] = cvtpk(h2,h3);
                Bx[2] = cvtpk(h4,1.0f); Bx[3] = cvtpk(h0,h1);
            } else {         // k8..15: [xh2,xh3,xh4, xl0..4]
                Bx[0] = cvtpk(h2,h3); Bx[1] = cvtpk(h4,l0);
                Bx[2] = cvtpk(l1,l2); Bx[3] = cvtpk(l3,l4);
            }
            #pragma unroll
            for (int ot = 0; ot < 4; ++ot) {
                u32x4 Av = *(const u32x4*)(smem + LDS_W1 + (ot*32+col)*32 + hib);
                acc[ot] = MFMA(BC16(Av), BC16(Bx), zf);
            }
        }
        convert();

        // ---- hidden layers 2..5, merged phases; stage the just-freed buffer ----
        LAYER(0, LDS_BUF0);
        __syncthreads();                                  // BUF0 free
        stageN(ws + WS_L(2), smem + LDS_BUF0, tid, 65536);
        LAYER(1, LDS_BUF1);
        __syncthreads();                                  // L(2) landed; BUF1 free
        stageN(ws + WS_L(3), smem + LDS_BUF1, tid, 65536);
        LAYER(2, LDS_BUF0);
        __syncthreads();                                  // L(3) landed; BUF0 free
        stageN(ws + WS_L(0), smem + LDS_BUF0, tid, 65536);
        LAYER(3, LDS_BUF1);
        __syncthreads();                                  // L(0)' landed; BUF1 free
        stageN(ws + WS_L(1), smem + LDS_BUF1, tid, 65536);

        // ---- heads: 13 outputs, rows 0..15; 2 interleaved accumulators ----
        f32x16 hA, hB;
        __builtin_amdgcn_s_setprio(1);
        #pragma unroll
        for (int k = 0; k < 8; ++k) {
            int so = (k*32 + hib) ^ sm;
            const char* rp = smem + LDS_HEADS + (col&15)*512;
            u32x4 HH = *(const u32x4*)(rp + so);
            u32x4 HL = *(const u32x4*)(rp + 256 + so);
            s16x8 bl = BC16(Bl[k]), bh = BC16(Bh[k]);
            if (k & 1) {
                hB = MFMA(BC16(HH), bl, (k==1)?zf:hB);
                hB = MFMA(BC16(HH), bh, hB);
                hB = MFMA(BC16(HL), bh, hB);
            } else {
                hA = MFMA(BC16(HH), bl, (k==0)?zf:hA);
                hA = MFMA(BC16(HH), bh, hA);
                hA = MFMA(BC16(HL), bh, hA);
            }
        }
        {
            u32 bw = (u32)*(const uint16_t*)(smem + LDS_BIAS + (512 + col)*2);
            u32x4 Ab; Ab[0] = hi ? 0u : bw; Ab[1]=0u; Ab[2]=0u; Ab[3]=0u;
            hA = MFMA(BC16(Ab), BC16(Bc), hA);
        }
        __builtin_amdgcn_s_setprio(0);
        f32x16 h6 = hA + hB;

        // ---- t0 + coeff.tb contraction, split across the hi=0/hi=1 lane pair ----
        // hi=0: c[0..3]=t0..3, c[4]=t8, c[5]=t9, c[6]=g1, c[7]=g2 ; hi=1: c[0..3]=t4..7, c[4]=g3
        if (p < NPTS) {
            const float* tbp = tb + (size_t)p*90;
            f32x16 c = h6;
            const float sixth = 0.16666666666666666f;
            const float third = 0.3333333333333333f;
            float s[9];
            if (hi == 0) {
                float g1 = c[6], g2 = c[7];
                s[0] = -g1*third + g2*sixth;
                s[4] =  g1*sixth - g2*third;
                s[8] =  g1*sixth + g2*sixth;
            } else {
                float g3 = c[4];
                s[0] =  g3*sixth;
                s[4] =  g3*sixth;
                s[8] = -g3*third;
            }
            s[1]=s[2]=s[3]=s[5]=s[6]=s[7]=0.f;
            #pragma unroll
            for (int j = 0; j < 4; ++j) {
                int trow = (hi ? 4 : 0) + j;
                float cf = c[j];
                const float* r = tbp + trow*9;
                f32x4u r0 = *(const f32x4u*)(r);
                f32x4u r1 = *(const f32x4u*)(r + 4);
                float r8 = r[8];
                s[0] += cf*r0.x; s[1] += cf*r0.y; s[2] += cf*r0.z; s[3] += cf*r0.w;
                s[4] += cf*r1.x; s[5] += cf*r1.y; s[6] += cf*r1.z; s[7] += cf*r1.w;
                s[8] += cf*r8;
            }
            if (hi == 0) {
                #pragma unroll
                for (int j = 4; j < 6; ++j) {
                    int trow = 4 + j;           // t8, t9
                    float cf = c[j];
                    const float* r = tbp + trow*9;
                    f32x4u r0 = *(const f32x4u*)(r);
                    f32x4u r1 = *(const f32x4u*)(r + 4);
                    float r8 = r[8];
                    s[0] += cf*r0.x; s[1] += cf*r0.y; s[2] += cf*r0.z; s[3] += cf*r0.w;
                    s[4] += cf*r1.x; s[5] += cf*r1.y; s[6] += cf*r1.z; s[7] += cf*r1.w;
                    s[8] += cf*r8;
                }
            }
            #pragma unroll
            for (int j = 0; j < 9; ++j) {  // merge hi0/hi1 partials (pairs share p)
                u32 uv = __builtin_bit_cast(u32, s[j]);
                auto rr = __builtin_amdgcn_permlane32_swap(uv, uv, false, false);
                s[j] = __builtin_bit_cast(float, (u32)rr[0]) + __builtin_bit_cast(float, (u32)rr[1]);
            }
            if (hi == 0) {
                float* op = out + (size_t)p*9;
                f32x4u o0, o1;
                o0.x=s[0]; o0.y=s[1]; o0.z=s[2]; o0.w=s[3];
                o1.x=s[4]; o1.y=s[5]; o1.z=s[6]; o1.w=s[7];
                *(f32x4u*)op       = o0;
                *(f32x4u*)(op + 4) = o1;
                op[8] = s[8];
            }
        }
    }
    __syncthreads();   // drain in-flight stages before workgroup teardown
}

extern "C" void kernel_launch(void* const* d_in, const int* in_sizes, int n_in,
                              void* d_out, int out_size, void* d_ws, size_t ws_size,
                              hipStream_t stream) {
    (void)in_sizes; (void)n_in; (void)out_size; (void)ws_size;
    char* ws = (char*)d_ws;
    hipLaunchKernelGGL(tbnn_prep, dim3(267), dim3(256), 0, stream,
        (const float*)d_in[2],  (const float*)d_in[3],
        (const float*)d_in[4],  (const float*)d_in[5],
        (const float*)d_in[6],  (const float*)d_in[7],
        (const float*)d_in[8],  (const float*)d_in[9],
        (const float*)d_in[10], (const float*)d_in[11],
        (const float*)d_in[12], (const float*)d_in[13],
        (const float*)d_in[14], (const float*)d_in[15],
        (const float*)d_in[16], (const float*)d_in[17],
        (const float*)d_in[18], (const float*)d_in[19],
        ws);
    (void)hipFuncSetAttribute((const void*)tbnn_main,
                              hipFuncAttributeMaxDynamicSharedMemorySize, LDS_TOTAL);
    hipLaunchKernelGGL(tbnn_main, dim3(NBLKS), dim3(TPB), LDS_TOTAL, stream,
        (const float*)d_in[0], (const float*)d_in[1], ws, (float*)d_out);
}